// Round 1
// baseline (377.838 us; speedup 1.0000x reference)
//
#include <hip/hip_runtime.h>

// Problem constants (from reference):
//   BATCH = 8192, DIM = 4096, NUM_PAIRS = 2048, GRID = 64
//   x:     (8192, 4096) f32  -> viewed as (B, P, 2), contiguous float2 per (b,p)
//   pairW: (2048, 2, 2)  f32  -> float4 per pair {W00, W01, W10, W11}
//   Y:     (2048, 64, 64) f32 -> 16 KiB slice per pair
//   out:   (8192, 2048)  f32
//
// out[b,p] = bilinear(Y[p], clip((x[b,p,:] @ W[p]) * 63, 0, 63))

#define PB_BATCH  8192
#define PB_PAIRS  2048
#define PB_G      64

__global__ __launch_bounds__(256) void pair_bilinear_kernel(
    const float* __restrict__ x,
    const float* __restrict__ pairW,
    const float* __restrict__ Y,
    float* __restrict__ out)
{
    const int idx = blockIdx.x * blockDim.x + threadIdx.x;   // idx = b*P + p
    const int p = idx & (PB_PAIRS - 1);

    // Coalesced vector loads: lane i -> consecutive float2 / float4.
    const float2 xv = reinterpret_cast<const float2*>(x)[idx];
    const float4 w  = reinterpret_cast<const float4*>(pairW)[p];

    // xp[j] = sum_i x[i] * W[i][j]  (W row-major: w = {W00, W01, W10, W11})
    float g0 = xv.x * w.x + xv.y * w.z;   // j = 0 (row coord)
    float g1 = xv.x * w.y + xv.y * w.w;   // j = 1 (col coord)

    g0 = fminf(fmaxf(g0 * 63.0f, 0.0f), 63.0f);
    g1 = fminf(fmaxf(g1 * 63.0f, 0.0f), 63.0f);

    // i0 = clip(floor(g), 0, 62); g >= 0 already, so only upper clamp needed.
    int r0 = (int)floorf(g0); r0 = (r0 > 62) ? 62 : r0;
    int c0 = (int)floorf(g1); c0 = (c0 > 62) ? 62 : c0;

    const float fr = g0 - (float)r0;
    const float fc = g1 - (float)c0;

    const float* Yp = Y + p * (PB_G * PB_G) + r0 * PB_G + c0;
    const float y00 = Yp[0];
    const float y01 = Yp[1];
    const float y10 = Yp[PB_G];
    const float y11 = Yp[PB_G + 1];

    const float omr = 1.0f - fr;
    const float omc = 1.0f - fc;
    out[idx] = y00 * omr * omc + y01 * omr * fc
             + y10 * fr  * omc + y11 * fr  * fc;
}

extern "C" void kernel_launch(void* const* d_in, const int* in_sizes, int n_in,
                              void* d_out, int out_size, void* d_ws, size_t ws_size,
                              hipStream_t stream) {
    const float* x     = (const float*)d_in[0];
    const float* pairW = (const float*)d_in[1];
    const float* Y     = (const float*)d_in[2];
    float* out = (float*)d_out;

    const int total  = PB_BATCH * PB_PAIRS;       // 16,777,216
    const int block  = 256;
    const int blocks = total / block;              // 65,536

    pair_bilinear_kernel<<<blocks, block, 0, stream>>>(x, pairW, Y, out);
}

// Round 2
// 275.270 us; speedup vs baseline: 1.3726x; 1.3726x over previous
//
#include <hip/hip_runtime.h>

// Problem constants:
//   BATCH = 8192, DIM = 4096, NUM_PAIRS = 2048, GRID = 64
//   x:     (8192, 4096) f32 -> (B, P, 2): one float2 per (b,p)
//   pairW: (2048, 2, 2)  f32 -> float4 per pair {W00,W01,W10,W11}
//   Y:     (2048, 64, 64) f32 -> 16 KiB slice per pair
//   out:   (8192, 2048)  f32
//
// Strategy: block = 1024 threads owns P_TILE=8 pairs; stages their Y slices
// (128 KiB) into LDS so the 4 bilinear gathers are ds_read_b32 (divergent
// addresses are native on the 32-bank LDS) instead of 64-way-divergent global
// loads that serialize in the texture/address unit. Thread map (b = t>>3,
// p = p0+(t&7)) keeps x loads and out stores coalesced (full 64B lines per
// 8-lane b-row group).

#define PB_BATCH  8192
#define PB_PAIRS  2048
#define PB_G      64
#define P_TILE    8
#define BLOCK     1024
#define LDS_FLOATS (P_TILE * PB_G * PB_G)   // 32768 floats = 128 KiB

__global__ __launch_bounds__(BLOCK, 1) void pair_bilinear_lds_kernel(
    const float* __restrict__ x,
    const float* __restrict__ pairW,
    const float* __restrict__ Y,
    float* __restrict__ out)
{
    extern __shared__ float sY[];           // 8 pairs x 4096 floats

    const int pt = blockIdx.x;              // pair-tile: 0..255
    const int p0 = pt * P_TILE;
    const int t  = threadIdx.x;

    // ---- Stage Y[p0 .. p0+7] into LDS: 8192 float4s, 8 per thread ----
    {
        const float4* Ysrc = reinterpret_cast<const float4*>(Y + (size_t)p0 * (PB_G * PB_G));
        float4* Ydst = reinterpret_cast<float4*>(sY);
        #pragma unroll
        for (int i = 0; i < LDS_FLOATS / 4 / BLOCK; ++i)
            Ydst[i * BLOCK + t] = Ysrc[i * BLOCK + t];
    }

    const int pl = t & (P_TILE - 1);        // pair lane within tile
    const int p  = p0 + pl;
    const float4 w = reinterpret_cast<const float4*>(pairW)[p];
    const float* __restrict__ myY = sY + pl * (PB_G * PB_G);

    __syncthreads();

    const int brow = t >> 3;                // 0..127
    const float2* __restrict__ x2 = reinterpret_cast<const float2*>(x);

    #pragma unroll 4
    for (int iter = 0; iter < PB_BATCH / (BLOCK / P_TILE); ++iter) {
        const int b = iter * (BLOCK / P_TILE) + brow;
        const int gi = b * PB_PAIRS + p;

        const float2 xv = x2[gi];

        float g0 = xv.x * w.x + xv.y * w.z;     // row coord
        float g1 = xv.x * w.y + xv.y * w.w;     // col coord
        g0 = fminf(fmaxf(g0 * 63.0f, 0.0f), 63.0f);
        g1 = fminf(fmaxf(g1 * 63.0f, 0.0f), 63.0f);

        int r0 = (int)floorf(g0); r0 = (r0 > 62) ? 62 : r0;
        int c0 = (int)floorf(g1); c0 = (c0 > 62) ? 62 : c0;

        const float fr = g0 - (float)r0;
        const float fc = g1 - (float)c0;

        const int base = r0 * PB_G + c0;
        const float y00 = myY[base];
        const float y01 = myY[base + 1];
        const float y10 = myY[base + PB_G];
        const float y11 = myY[base + PB_G + 1];

        const float omr = 1.0f - fr;
        const float omc = 1.0f - fc;
        out[gi] = y00 * omr * omc + y01 * omr * fc
                + y10 * fr  * omc + y11 * fr  * fc;
    }
}

extern "C" void kernel_launch(void* const* d_in, const int* in_sizes, int n_in,
                              void* d_out, int out_size, void* d_ws, size_t ws_size,
                              hipStream_t stream) {
    const float* x     = (const float*)d_in[0];
    const float* pairW = (const float*)d_in[1];
    const float* Y     = (const float*)d_in[2];
    float* out = (float*)d_out;

    static_assert(LDS_FLOATS * sizeof(float) == 131072, "128 KiB LDS");

    // Opt in to >64 KiB dynamic LDS (gfx950 has 160 KiB/CU). Idempotent,
    // host-side only — safe under graph capture.
    (void)hipFuncSetAttribute(
        reinterpret_cast<const void*>(&pair_bilinear_lds_kernel),
        hipFuncAttributeMaxDynamicSharedMemorySize,
        LDS_FLOATS * sizeof(float));

    const int blocks = PB_PAIRS / P_TILE;   // 256 = one block per CU
    pair_bilinear_lds_kernel<<<blocks, BLOCK, LDS_FLOATS * sizeof(float), stream>>>(
        x, pairW, Y, out);
}

// Round 3
// 272.128 us; speedup vs baseline: 1.3885x; 1.0115x over previous
//
#include <hip/hip_runtime.h>

// BATCH=8192, DIM=4096, NUM_PAIRS=2048, GRID=64
//   x: (B, P, 2) f32   pairW: (P,2,2) f32   Y: (P,64,64) f32   out: (B,P) f32
//
// R3: fp16 Y in LDS (64 KiB / 8 pairs) -> 2 blocks/CU = 32 waves/CU.
// Each thread owns 2 adjacent pairs: one float4 x-load, float2 store.
// Grid 512 = 256 pair-tiles x 2 batch-tiles; same-Y blocks share an XCD.

#define PB_BATCH  8192
#define PB_PAIRS  2048
#define PB_G      64
#define P_TILE    8
#define BLOCK     1024
#define BTILES    2
#define BT_ROWS   (PB_BATCH / BTILES)          // 4096
#define LDS_HALVES (P_TILE * PB_G * PB_G)      // 32768 halves = 64 KiB

typedef _Float16 half4_t __attribute__((ext_vector_type(4)));

__global__ __launch_bounds__(BLOCK, 8) void pair_bilinear_fp16lds_kernel(
    const float* __restrict__ x,
    const float* __restrict__ pairW,
    const float* __restrict__ Y,
    float* __restrict__ out)
{
    extern __shared__ _Float16 sY[];           // [8 pairs][64][64] fp16

    const int ptile = blockIdx.x & 255;
    const int btile = blockIdx.x >> 8;
    const int p0 = ptile * P_TILE;
    const int t  = threadIdx.x;

    // ---- Stage Y[p0..p0+7] f32 -> fp16 LDS: 8192 float4 reads, 8/thread ----
    {
        const float4* Ysrc = reinterpret_cast<const float4*>(Y + (size_t)p0 * (PB_G * PB_G));
        half4_t* Ydst = reinterpret_cast<half4_t*>(sY);
        #pragma unroll
        for (int i = 0; i < LDS_HALVES / 4 / BLOCK; ++i) {
            const float4 v = Ysrc[i * BLOCK + t];
            half4_t h;
            h.x = (_Float16)v.x; h.y = (_Float16)v.y;
            h.z = (_Float16)v.z; h.w = (_Float16)v.w;
            Ydst[i * BLOCK + t] = h;
        }
    }

    const int slot = t & 3;                    // 2 pairs per slot -> 8 pairs
    const int brow = t >> 2;                   // 0..255
    const int pA = p0 + 2 * slot;              // first pair of this thread

    const float4 wA = reinterpret_cast<const float4*>(pairW)[pA];
    const float4 wB = reinterpret_cast<const float4*>(pairW)[pA + 1];
    const _Float16* __restrict__ yA = sY + (2 * slot) * (PB_G * PB_G);
    const _Float16* __restrict__ yB = yA + PB_G * PB_G;

    __syncthreads();

    const float4* __restrict__ x4 = reinterpret_cast<const float4*>(x);
    float2* __restrict__ out2 = reinterpret_cast<float2*>(out);
    const int vecbase = (p0 >> 1) + slot;      // float4/float2 column index

    #pragma unroll 4
    for (int it = 0; it < BT_ROWS / (BLOCK / 4); ++it) {
        const int b = btile * BT_ROWS + it * (BLOCK / 4) + brow;
        const float4 xv = x4[b * (PB_PAIRS / 2) + vecbase];  // pairA:(x,y) pairB:(z,w)

        // ---- pair A ----
        float gA0 = xv.x * wA.x + xv.y * wA.z;
        float gA1 = xv.x * wA.y + xv.y * wA.w;
        gA0 = fminf(fmaxf(gA0 * 63.0f, 0.0f), 63.0f);
        gA1 = fminf(fmaxf(gA1 * 63.0f, 0.0f), 63.0f);
        int rA = (int)gA0; rA = (rA > 62) ? 62 : rA;
        int cA = (int)gA1; cA = (cA > 62) ? 62 : cA;
        const float frA = gA0 - (float)rA, fcA = gA1 - (float)cA;
        const int baseA = rA * PB_G + cA;
        const float a00 = (float)yA[baseA];
        const float a01 = (float)yA[baseA + 1];
        const float a10 = (float)yA[baseA + PB_G];
        const float a11 = (float)yA[baseA + PB_G + 1];

        // ---- pair B ----
        float gB0 = xv.z * wB.x + xv.w * wB.z;
        float gB1 = xv.z * wB.y + xv.w * wB.w;
        gB0 = fminf(fmaxf(gB0 * 63.0f, 0.0f), 63.0f);
        gB1 = fminf(fmaxf(gB1 * 63.0f, 0.0f), 63.0f);
        int rB = (int)gB0; rB = (rB > 62) ? 62 : rB;
        int cB = (int)gB1; cB = (cB > 62) ? 62 : cB;
        const float frB = gB0 - (float)rB, fcB = gB1 - (float)cB;
        const int baseB = rB * PB_G + cB;
        const float b00 = (float)yB[baseB];
        const float b01 = (float)yB[baseB + 1];
        const float b10 = (float)yB[baseB + PB_G];
        const float b11 = (float)yB[baseB + PB_G + 1];

        float2 o;
        o.x = (a00 * (1.0f - frA) + a10 * frA) * (1.0f - fcA)
            + (a01 * (1.0f - frA) + a11 * frA) * fcA;
        o.y = (b00 * (1.0f - frB) + b10 * frB) * (1.0f - fcB)
            + (b01 * (1.0f - frB) + b11 * frB) * fcB;
        out2[b * (PB_PAIRS / 2) + vecbase] = o;
    }
}

extern "C" void kernel_launch(void* const* d_in, const int* in_sizes, int n_in,
                              void* d_out, int out_size, void* d_ws, size_t ws_size,
                              hipStream_t stream) {
    const float* x     = (const float*)d_in[0];
    const float* pairW = (const float*)d_in[1];
    const float* Y     = (const float*)d_in[2];
    float* out = (float*)d_out;

    (void)hipFuncSetAttribute(
        reinterpret_cast<const void*>(&pair_bilinear_fp16lds_kernel),
        hipFuncAttributeMaxDynamicSharedMemorySize,
        LDS_HALVES * sizeof(_Float16));

    const int blocks = (PB_PAIRS / P_TILE) * BTILES;   // 256 * 2 = 512
    pair_bilinear_fp16lds_kernel<<<blocks, BLOCK, LDS_HALVES * sizeof(_Float16), stream>>>(
        x, pairW, Y, out);
}